// Round 14
// baseline (1514.876 us; speedup 1.0000x reference)
//
#include <hip/hip_runtime.h>
#include <hip/hip_bf16.h>

#define D_DIM 3072
#define NTRAIN 16384
#define NTEST 8192

typedef __attribute__((ext_vector_type(8))) short short8;
typedef __attribute__((ext_vector_type(4))) float f32x4;
typedef __attribute__((ext_vector_type(2))) long long ll2;

__device__ __forceinline__ unsigned short f2bf(float f) {
  union { float f; unsigned u; } x; x.f = f;
  unsigned r = x.u + 0x7FFFu + ((x.u >> 16) & 1u);
  return (unsigned short)(r >> 16);
}

__device__ __forceinline__ void gload16(const void* g, void* l) {
  __builtin_amdgcn_global_load_lds(
      (const __attribute__((address_space(1))) void*)g,
      (__attribute__((address_space(3))) void*)l, 16, 0, 0);
}

// T1: bijective chunked XCD swizzle + 8x8 supertile ordering (gx%8==0, gy%8==0).
__device__ __forceinline__ void swz_tile(int& tileY, int& tileX) {
  const int gx = gridDim.x, gy = gridDim.y;
  const int L = blockIdx.y * gx + blockIdx.x;
  const int q = (gx * gy) >> 3;
  const int s = (L & 7) * q + (L >> 3);
  const int sid = s >> 6;
  const int t = s & 63;
  const int scols = gx >> 3;
  const int sy = sid / scols, sx = sid - sy * scols;
  tileY = sy * 8 + (t >> 3);
  tileX = sx * 8 + (t & 7);
}

// ---------------- pass 0 ----------------
__global__ void k_convert(const float* __restrict__ in, unsigned short* __restrict__ out, long n4) {
  long i = (long)blockIdx.x * blockDim.x + threadIdx.x;
  long stride = (long)gridDim.x * blockDim.x;
  for (; i < n4; i += stride) {
    float4 v = reinterpret_cast<const float4*>(in)[i];
    ushort4 o;
    o.x = f2bf(v.x); o.y = f2bf(v.y); o.z = f2bf(v.z); o.w = f2bf(v.w);
    reinterpret_cast<ushort4*>(out)[i] = o;
  }
}

// f32 -> fp8 e4m3 (OCP, saturating), 8 elems/thread-iter
__global__ void k_convert8(const float* __restrict__ in, unsigned char* __restrict__ out, long n8) {
  long i = (long)blockIdx.x * blockDim.x + threadIdx.x;
  long stride = (long)gridDim.x * blockDim.x;
  for (; i < n8; i += stride) {
    float4 a = reinterpret_cast<const float4*>(in)[i * 2];
    float4 b = reinterpret_cast<const float4*>(in)[i * 2 + 1];
    int w0 = __builtin_amdgcn_cvt_pk_fp8_f32(a.x, a.y, 0, false);
    w0 = __builtin_amdgcn_cvt_pk_fp8_f32(a.z, a.w, w0, true);
    int w1 = __builtin_amdgcn_cvt_pk_fp8_f32(b.x, b.y, 0, false);
    w1 = __builtin_amdgcn_cvt_pk_fp8_f32(b.z, b.w, w1, true);
    reinterpret_cast<int2*>(out)[i] = make_int2(w0, w1);
  }
}

__global__ void k_copy4(const float4* __restrict__ in, float4* __restrict__ out, long n4) {
  long i = (long)blockIdx.x * blockDim.x + threadIdx.x;
  long stride = (long)gridDim.x * blockDim.x;
  for (; i < n4; i += stride) out[i] = in[i];
}

__global__ void k_transpose_bf16(const float* __restrict__ M, unsigned short* __restrict__ Mt) {
  __shared__ float t[32][33];
  int bx = blockIdx.x * 32, by = blockIdx.y * 32;
  int tx = threadIdx.x, ty = threadIdx.y;
#pragma unroll
  for (int i = 0; i < 32; i += 8)
    t[ty + i][tx] = M[(size_t)(by + ty + i) * D_DIM + bx + tx];
  __syncthreads();
#pragma unroll
  for (int i = 0; i < 32; i += 8)
    Mt[(size_t)(bx + ty + i) * D_DIM + by + tx] = f2bf(t[tx][ty + i]);
}

// ------- R6 xm main loop: 512 threads, 32x64 wave tiles, bf16, T2 swizzle -------
__device__ __forceinline__ void mainloopXM(const unsigned short* __restrict__ A,
                                           const unsigned short* __restrict__ B,
                                           int K, int rowBase, int colBase,
                                           unsigned short* As, unsigned short* Bs,
                                           f32x4 acc[2][4]) {
  const int tid = threadIdx.x;
  const int lane = tid & 63;
  const int wave = tid >> 6;
  const int wm = wave >> 1, wn = wave & 1;
  const int sr = tid >> 3;
  const int ssl = tid & 7;
  const int scol = ((ssl ^ (sr & 7)) * 8);
  const unsigned short* ga = A + (size_t)(rowBase + sr) * K + scol;
  const unsigned short* gb = B + (size_t)(colBase + sr) * K + scol;
  const int arow = wm * 32 + (lane & 15);
  const int brow = wn * 64 + (lane & 15);
  const int lsw = lane & 7;
  const int lhi = lane >> 4;
  for (int k0 = 0; k0 < K; k0 += 64) {
#pragma unroll
    for (int c = 0; c < 2; ++c) {
      gload16(ga + (size_t)c * 64 * K + k0, As + c * 4096 + tid * 8);
      gload16(gb + (size_t)c * 64 * K + k0, Bs + c * 4096 + tid * 8);
    }
    __syncthreads();
#pragma unroll
    for (int kk = 0; kk < 2; ++kk) {
      short8 af[2], bfr[4];
      const int sl = ((lhi + kk * 4) ^ lsw) * 8;
#pragma unroll
      for (int i = 0; i < 2; ++i)
        af[i] = *reinterpret_cast<const short8*>(&As[(arow + i * 16) * 64 + sl]);
#pragma unroll
      for (int j = 0; j < 4; ++j)
        bfr[j] = *reinterpret_cast<const short8*>(&Bs[(brow + j * 16) * 64 + sl]);
#pragma unroll
      for (int i = 0; i < 2; ++i)
#pragma unroll
        for (int j = 0; j < 4; ++j)
          acc[i][j] = __builtin_amdgcn_mfma_f32_16x16x32_bf16(af[i], bfr[j], acc[i][j], 0, 0, 0);
    }
    __syncthreads();
  }
}

// ---- GEMM1: X @ M (R6-exact). Epilogue: norm2 (+ optional fp8 sM write) ----
template <bool WRITE_SM>
__global__ __launch_bounds__(512, 4) void k_gemm_xm(const unsigned short* __restrict__ A,
                                                    const unsigned short* __restrict__ Bt,
                                                    const float* __restrict__ Xf,
                                                    unsigned char* __restrict__ smOut,
                                                    float* __restrict__ norm) {
  __shared__ unsigned short As[128 * 64], Bs[128 * 64];
  int tileY, tileX;
  swz_tile(tileY, tileX);
  const int rowBase = tileY * 128, colBase = tileX * 128;
  f32x4 acc[2][4] = {};
  mainloopXM(A, Bt, D_DIM, rowBase, colBase, As, Bs, acc);
  const int tid = threadIdx.x, lane = tid & 63;
  const int wave = tid >> 6;
  const int wm = wave >> 1, wn = wave & 1;
  const int r0 = wm * 32 + (lane >> 4) * 4;
  const int c0 = colBase + wn * 64 + (lane & 15);
#pragma unroll
  for (int mi = 0; mi < 2; ++mi) {
#pragma unroll
    for (int r = 0; r < 4; ++r) {
      const size_t grow = rowBase + r0 + mi * 16 + r;
      float v = 0.f;
#pragma unroll
      for (int ni = 0; ni < 4; ++ni) {
        float a = acc[mi][ni][r];
        int gcol = c0 + ni * 16;
        v += a * Xf[grow * D_DIM + gcol];
        if (WRITE_SM) {
          int p = __builtin_amdgcn_cvt_pk_fp8_f32(a, a, 0, false);
          smOut[grow * D_DIM + gcol] = (unsigned char)(p & 0xFF);
        }
      }
      v += __shfl_xor(v, 1); v += __shfl_xor(v, 2);
      v += __shfl_xor(v, 4); v += __shfl_xor(v, 8);
      if ((lane & 15) == 0) atomicAdd(&norm[grow], v);
    }
  }
}

// ======== GEMM2: fp8 e4m3, 128x128 tile, BK=128, double-buffered LDS with ========
// derived counted-vmcnt schedule (T3/T4 minimum) + T5 setprio.
// Per iter t: issue A(t+1) [2 gloads, into buf freed by prev turnover barrier]
//   -> vmcnt(2) [retires exactly A(t),B(t); in-order retire]
//   -> barrier -> kp0 compute -> issue B(t+1) -> kp1 compute -> turnover barrier.
// Loads never drained to 0 in the main loop; each has ~1 iter of flight.
__global__ __launch_bounds__(512, 4) void k_gemm_cross(const unsigned char* __restrict__ sM8,
                                                       const unsigned char* __restrict__ xte8,
                                                       const float* __restrict__ Y,
                                                       const float* __restrict__ sn2,
                                                       const float* __restrict__ cn2,
                                                       float* __restrict__ part) {
  __shared__ unsigned char As[2 * 128 * 128], Bs[2 * 128 * 128];  // 32 + 32 KiB
  const int tid = threadIdx.x;
  int tileY, tileX;
  swz_tile(tileY, tileX);
  const int rowBase = tileY * 128, colBase = tileX * 128;
  const int lane = tid & 63;
  const int wave = tid >> 6;
  const int wm = wave >> 1, wn = wave & 1;   // 4M x 2N of 32x64
  const int l15 = lane & 15, lhi = lane >> 4;
  const int arow = wm * 32 + l15;
  const int brow = wn * 64 + l15;
  // staging: row = c*64 + (tid>>3), phys slot = tid&7, source chunk = slot^(row&7)
  const int srow = tid >> 3;                 // 0..63
  const int ssl = tid & 7;
  const unsigned char* ga = sM8 + (size_t)(rowBase + srow) * D_DIM + ((ssl ^ (srow & 7)) * 16);
  const unsigned char* gb = xte8 + (size_t)(colBase + srow) * D_DIM + ((ssl ^ (srow & 7)) * 16);

  f32x4 acc[2][4] = {};
  const int nt = D_DIM / 128;                // 24

#define CROSS_KP(Ac, Bc, kp)                                                        \
  {                                                                                \
    ll2 a16[2], b16[4];                                                            \
    const int l = (kp) * 4 + lhi;                                                  \
    _Pragma("unroll") for (int i = 0; i < 2; ++i) {                                \
      const int row = arow + i * 16;                                               \
      a16[i] = *reinterpret_cast<const ll2*>(&(Ac)[row * 128 + ((l ^ (row & 7)) * 16)]); \
    }                                                                              \
    _Pragma("unroll") for (int j = 0; j < 4; ++j) {                                \
      const int row = brow + j * 16;                                               \
      b16[j] = *reinterpret_cast<const ll2*>(&(Bc)[row * 128 + ((l ^ (row & 7)) * 16)]); \
    }                                                                              \
    __builtin_amdgcn_s_setprio(1);                                                 \
    _Pragma("unroll") for (int kk = 0; kk < 2; ++kk)                               \
      _Pragma("unroll") for (int i = 0; i < 2; ++i)                                \
        _Pragma("unroll") for (int j = 0; j < 4; ++j)                              \
          acc[i][j] = __builtin_amdgcn_mfma_f32_16x16x32_fp8_fp8(a16[i][kk], b16[j][kk], \
                                                                 acc[i][j], 0, 0, 0); \
    __builtin_amdgcn_s_setprio(0);                                                 \
  }

  // prologue: stage tile 0 into buffer 0 (order: A then B)
  gload16(ga, As + tid * 16);
  gload16(ga + (size_t)64 * D_DIM, As + 8192 + tid * 16);
  gload16(gb, Bs + tid * 16);
  gload16(gb + (size_t)64 * D_DIM, Bs + 8192 + tid * 16);

  for (int t = 0; t < nt - 1; ++t) {
    const int p = t & 1;
    const unsigned char* Ac = As + p * 16384;
    const unsigned char* Bc = Bs + p * 16384;
    unsigned char* An = As + (p ^ 1) * 16384;
    unsigned char* Bn = Bs + (p ^ 1) * 16384;
    const int k1 = (t + 1) * 128;
    // issue A(t+1) — target buffer freed by previous turnover barrier
    gload16(ga + k1, An + tid * 16);
    gload16(ga + (size_t)64 * D_DIM + k1, An + 8192 + tid * 16);
    asm volatile("s_waitcnt vmcnt(2)" ::: "memory");   // A(t),B(t) retired
    __builtin_amdgcn_s_barrier();
    __builtin_amdgcn_sched_barrier(0);
    CROSS_KP(Ac, Bc, 0)
    // issue B(t+1)
    gload16(gb + k1, Bn + tid * 16);
    gload16(gb + (size_t)64 * D_DIM + k1, Bn + 8192 + tid * 16);
    CROSS_KP(Ac, Bc, 1)
    __builtin_amdgcn_s_barrier();          // turnover: all waves done with buf p
    __builtin_amdgcn_sched_barrier(0);
  }
  {  // peeled last tile: no prefetch, full drain
    const int p = (nt - 1) & 1;
    const unsigned char* Ac = As + p * 16384;
    const unsigned char* Bc = Bs + p * 16384;
    asm volatile("s_waitcnt vmcnt(0)" ::: "memory");
    __builtin_amdgcn_s_barrier();
    __builtin_amdgcn_sched_barrier(0);
    CROSS_KP(Ac, Bc, 0)
    CROSS_KP(Ac, Bc, 1)
  }
#undef CROSS_KP
  __syncthreads();

  // ---- fused epilogue (R13-exact): kv = exp2(-log2e/10*sqrt(d2)); col partials ----
  float* ylds = reinterpret_cast<float*>(As);                 // [128][12] padded
  float* snlds = ylds + 128 * 12;                             // [128]
  float (*pcol)[11] = reinterpret_cast<float(*)[11]>(Bs);     // [128][11]
  for (int i = tid; i < 1280; i += 512)
    ylds[(i / 10) * 12 + (i % 10)] = Y[(size_t)rowBase * 10 + i];
  if (tid < 128) snlds[tid] = sn2[rowBase + tid];
  for (int i = tid; i < 128 * 11; i += 512) (&pcol[0][0])[i] = 0.f;
  __syncthreads();
  const int r0 = wm * 32 + lhi * 4;
  const int c0l = wn * 64 + l15;
#pragma unroll
  for (int ni = 0; ni < 4; ++ni) {
    const float cnv = cn2[colBase + c0l + ni * 16];
    float ps[11];
#pragma unroll
    for (int c = 0; c < 11; ++c) ps[c] = 0.f;
#pragma unroll
    for (int mi = 0; mi < 2; ++mi) {
#pragma unroll
      for (int r = 0; r < 4; ++r) {
        const int lrow = r0 + mi * 16 + r;
        float d2 = snlds[lrow] + cnv - 2.f * acc[mi][ni][r];
        float kv = exp2f(-0.14426950408889634f * sqrtf(fmaxf(d2, 0.f)));
        ps[10] += kv;
        f32x4 y0 = *reinterpret_cast<const f32x4*>(&ylds[lrow * 12]);
        f32x4 y1 = *reinterpret_cast<const f32x4*>(&ylds[lrow * 12 + 4]);
        float2 y2 = *reinterpret_cast<const float2*>(&ylds[lrow * 12 + 8]);
#pragma unroll
        for (int c = 0; c < 4; ++c) ps[c] += kv * y0[c];
#pragma unroll
        for (int c = 0; c < 4; ++c) ps[4 + c] += kv * y1[c];
        ps[8] += kv * y2.x;
        ps[9] += kv * y2.y;
      }
    }
#pragma unroll
    for (int c = 0; c < 11; ++c) {
      float v = ps[c];
      v += __shfl_xor(v, 16);
      v += __shfl_xor(v, 32);
      if (lane < 16) atomicAdd(&pcol[wn * 64 + ni * 16 + lane][c], v);
    }
  }
  __syncthreads();
  if (tid < 128) {
    int gcol = colBase + tid;
#pragma unroll
    for (int c = 0; c < 11; ++c)
      part[((size_t)tileY * 11 + c) * NTEST + gcol] = pcol[tid][c];
  }
}

// ---------------- final reduce ----------------
__global__ void k_reduce(const float* __restrict__ part, float* __restrict__ out) {
  int t = blockIdx.x * blockDim.x + threadIdx.x;
  float num[10] = {0, 0, 0, 0, 0, 0, 0, 0, 0, 0};
  float den = 0.f;
  for (int it = 0; it < NTRAIN / 128; ++it) {
    const float* p = part + (size_t)it * 11 * NTEST + t;
#pragma unroll
    for (int c = 0; c < 10; ++c) num[c] += p[(size_t)c * NTEST];
    den += p[(size_t)10 * NTEST];
  }
  float inv = 1.f / den;
#pragma unroll
  for (int c = 0; c < 10; ++c) out[(size_t)t * 10 + c] = num[c] * inv;
}

extern "C" void kernel_launch(void* const* d_in, const int* in_sizes, int n_in,
                              void* d_out, int out_size, void* d_ws, size_t ws_size,
                              hipStream_t stream) {
  const float* x_train = (const float*)d_in[0];
  const float* y_train = (const float*)d_in[1];
  const float* x_test  = (const float*)d_in[2];
  const float* M       = (const float*)d_in[3];
  float* out = (float*)d_out;

  char* ws = (char*)d_ws;
  unsigned short* xtr16 = (unsigned short*)(ws + 0);          // 100663296
  unsigned short* xte16 = (unsigned short*)(ws + 100663296);  // 50331648
  unsigned short* Mt16  = (unsigned short*)(ws + 150994944);  // 18874368
  unsigned char*  sM8   = (unsigned char*)(ws + 169869312);   // 16384*3072 = 50331648
  unsigned char*  xte8  = (unsigned char*)(ws + 220200960);   // 8192*3072  = 25165824
  float* s_n2 = (float*)(ws + 245366784);                     // 65536
  float* c_n2 = (float*)(ws + 245432320);                     // 32768
  float* part = (float*)(ws + 245465088);                     // 128*11*8192*4 = 46137344

  hipMemsetAsync(ws + 245366784, 0, 98304, stream);  // s_n2 + c_n2

  k_convert<<<2048, 256, 0, stream>>>(x_train, xtr16, (long)NTRAIN * D_DIM / 4);
  k_convert<<<2048, 256, 0, stream>>>(x_test, xte16, (long)NTEST * D_DIM / 4);
  k_convert8<<<1024, 256, 0, stream>>>(x_test, xte8, (long)NTEST * D_DIM / 8);
  k_transpose_bf16<<<dim3(96, 96), dim3(32, 8), 0, stream>>>(M, Mt16);
  k_copy4<<<2048, 256, 0, stream>>>((const float4*)M, (float4*)(out + 81920),
                                    (long)D_DIM * D_DIM / 4);

  k_gemm_xm<true><<<dim3(24, 128), 512, 0, stream>>>(xtr16, Mt16, x_train, sM8, s_n2);
  k_gemm_xm<false><<<dim3(24, 64), 512, 0, stream>>>(xte16, Mt16, x_test, nullptr, c_n2);

  k_gemm_cross<<<dim3(64, 128), 512, 0, stream>>>(sM8, xte8, y_train, s_n2, c_n2, part);
  k_reduce<<<32, 256, 0, stream>>>(part, out);
}